// Round 4
// baseline (909.680 us; speedup 1.0000x reference)
//
#include <hip/hip_runtime.h>

// APPNP propagation: h <- (1-alpha) * A @ h + alpha * x, K=10 steps.
// R3: CSR gather, bf16 h buffers (1066.6). R4: nt loads REGRESSED (1270.9).
// R5: unroll x8 + bf16 xb -> 967.6. R6: padded CSR (no hist/scan) -> 885.7,
//     but MLP-4 scatter regressed 120->141 us (occupancy 71->44%: grid/4
//     traded TLP for MLP; bound by random partial-line writebacks anyway).
// R7: (a) revert scatter to 1-edge/thread; (b) SORT each row's edges by col
//     (in-wave 64-lane bitonic over padded CSR, one extra ~15us kernel).
//     All waves then sweep the col space in loose lockstep -> instantaneous
//     gather working set is a narrow col band that fits each XCD's 4MB L2
//     -> ~15/16 of the 425 MB/step gather traffic becomes L2 hits.
//     spmm kernel byte-for-byte unchanged (isolates the ordering effect).

#define N_NODES 100000
#define N_EDGES 1600000
#define D_FEAT  128
#define ALPHA   0.1f
#define K_STEPS 10
#define MAXDEG  64   // P(Poisson(16) >= 64) ~ 1e-19; guarded anyway

#define SCAN_ELEMS 512
#define SCAN_NBLK  ((N_NODES + SCAN_ELEMS - 1) / SCAN_ELEMS)  // 196

static __device__ __forceinline__ float bf2f(unsigned u16) {
    return __uint_as_float(u16 << 16);
}
static __device__ __forceinline__ unsigned f2bf(float f) {
    unsigned u = __float_as_uint(f);
    return (u + 0x7fffu + ((u >> 16) & 1u)) >> 16;  // round-to-nearest-even
}

// ---------- padded CSR build: one atomic pass, no hist/scan ----------

__global__ __launch_bounds__(256) void scatter_padded(const int* __restrict__ rows,
                                                      const int* __restrict__ cols,
                                                      const float* __restrict__ w,
                                                      int* __restrict__ cnt,
                                                      int2* __restrict__ csrp) {
    int e = blockIdx.x * 256 + threadIdx.x;
    if (e < N_EDGES) {
        int r = rows[e];
        int pos = atomicAdd(&cnt[r], 1);
        if (pos < MAXDEG) {
            int2 cw;
            cw.x = cols[e];
            cw.y = __float_as_int((1.0f - ALPHA) * w[e]);  // fold 0.9 into weight
            csrp[((size_t)r << 6) + pos] = cw;
        }
    }
}

// Sort each padded row's edges by col: 64-lane in-wave bitonic on packed
// (col << 32) | w. Invalid lanes get key INT_MAX -> sort to the tail.
__global__ __launch_bounds__(256) void sort_rows(const int* __restrict__ cnt,
                                                 int2* __restrict__ csrp) {
    int row = (blockIdx.x * 256 + threadIdx.x) >> 6;
    int lane = threadIdx.x & 63;
    if (row >= N_NODES) return;
    int cn = cnt[row];
    cn = (cn < MAXDEG) ? cn : MAXDEG;
    if (cn <= 1) return;  // wave-uniform
    size_t base = (size_t)row << 6;
    int2 cw = csrp[base + lane];
    unsigned key = (lane < cn) ? (unsigned)cw.x : 0x7fffffffu;
    unsigned long long v =
        ((unsigned long long)key << 32) | (unsigned long long)(unsigned)cw.y;
    #pragma unroll
    for (int k = 2; k <= 64; k <<= 1) {
        #pragma unroll
        for (int j = k >> 1; j > 0; j >>= 1) {
            unsigned long long o = __shfl_xor(v, j, 64);
            bool lower = ((lane & j) == 0);
            bool dir = ((lane & k) == 0);
            unsigned long long mn = (v < o) ? v : o;
            unsigned long long mx = (v < o) ? o : v;
            v = (lower == dir) ? mn : mx;
        }
    }
    if (lane < cn) {
        int2 out;
        out.x = (int)(v >> 32);
        out.y = (int)(v & 0xffffffffu);
        csrp[base + lane] = out;
    }
}

// ---------- compact CSR build (fallback tier, R5 path) ----------

__global__ __launch_bounds__(256) void hist_kernel(const int* __restrict__ rows,
                                                   int* __restrict__ deg) {
    int e = blockIdx.x * 256 + threadIdx.x;
    if (e < N_EDGES) atomicAdd(&deg[rows[e]], 1);
}

__global__ __launch_bounds__(256) void scan_partial(const int* __restrict__ deg,
                                                    int* __restrict__ partial) {
    __shared__ int s[256];
    int b = blockIdx.x, t = threadIdx.x;
    int i0 = b * SCAN_ELEMS + t * 2;
    int v0 = (i0 < N_NODES) ? deg[i0] : 0;
    int v1 = (i0 + 1 < N_NODES) ? deg[i0 + 1] : 0;
    s[t] = v0 + v1;
    __syncthreads();
    for (int off = 128; off > 0; off >>= 1) {
        if (t < off) s[t] += s[t + off];
        __syncthreads();
    }
    if (t == 0) partial[b] = s[0];
}

__global__ __launch_bounds__(256) void scan_top(int* __restrict__ partial) {
    __shared__ int s[256];
    int t = threadIdx.x;
    s[t] = (t < SCAN_NBLK) ? partial[t] : 0;
    __syncthreads();
    for (int off = 1; off < 256; off <<= 1) {
        int v = (t >= off) ? s[t - off] : 0;
        __syncthreads();
        s[t] += v;
        __syncthreads();
    }
    if (t < SCAN_NBLK) partial[t] = (t == 0) ? 0 : s[t - 1];
}

__global__ __launch_bounds__(256) void scan_final(int* __restrict__ deg_cursor,
                                                  const int* __restrict__ partial,
                                                  int* __restrict__ row_ptr) {
    __shared__ int s[256];
    int b = blockIdx.x, t = threadIdx.x;
    int i0 = b * SCAN_ELEMS + t * 2;
    int v0 = (i0 < N_NODES) ? deg_cursor[i0] : 0;
    int v1 = (i0 + 1 < N_NODES) ? deg_cursor[i0 + 1] : 0;
    int pair = v0 + v1;
    s[t] = pair;
    __syncthreads();
    for (int off = 1; off < 256; off <<= 1) {
        int v = (t >= off) ? s[t - off] : 0;
        __syncthreads();
        s[t] += v;
        __syncthreads();
    }
    int ex = partial[b] + s[t] - pair;  // exclusive prefix of element 2t
    if (i0 < N_NODES)     { row_ptr[i0] = ex;          deg_cursor[i0] = ex; }
    if (i0 + 1 < N_NODES) { row_ptr[i0 + 1] = ex + v0; deg_cursor[i0 + 1] = ex + v0; }
    if (b == 0 && t == 0) row_ptr[N_NODES] = N_EDGES;
}

__global__ __launch_bounds__(256) void scatter_kernel(const int* __restrict__ rows,
                                                      const int* __restrict__ cols,
                                                      const float* __restrict__ w,
                                                      int* __restrict__ cursor,
                                                      int2* __restrict__ csr) {
    int e = blockIdx.x * 256 + threadIdx.x;
    if (e < N_EDGES) {
        int pos = atomicAdd(&cursor[rows[e]], 1);
        int2 cw;
        cw.x = cols[e];
        cw.y = __float_as_int((1.0f - ALPHA) * w[e]);  // fold 0.9 into the weight
        csr[pos] = cw;
    }
}

// x fp32 -> packed 2xbf16 per u32 (row-major, 64 u32 per row)
__global__ __launch_bounds__(256) void x_to_bf16(const float2* __restrict__ x2,
                                                 unsigned* __restrict__ xb, int n) {
    int i = blockIdx.x * 256 + threadIdx.x;
    if (i < n) {
        float2 v = x2[i];
        xb[i] = f2bf(v.x) | (f2bf(v.y) << 16);
    }
}

// ---------- propagation step: one wave per row ----------
// SRC_BF/DST_BF: gather src / dst format. X_BF: alpha*x term source format.
// PAD: padded CSR (rp = cnt[], edges at row*64) vs compact (rp = row_ptr[]).

template <bool SRC_BF, bool DST_BF, bool X_BF, bool PAD>
__global__ __launch_bounds__(256) void row_spmm_t(const int* __restrict__ rp,
                                                  const int2* __restrict__ csr,
                                                  const void* __restrict__ xsrc,
                                                  const void* __restrict__ src,
                                                  void* __restrict__ dst) {
    int row = (blockIdx.x * 256 + threadIdx.x) >> 6;
    int lane = threadIdx.x & 63;
    if (row >= N_NODES) return;
    int beg, end;
    if (PAD) {
        int cn = rp[row];
        cn = (cn < MAXDEG) ? cn : MAXDEG;
        beg = row << 6;
        end = beg + cn;
    } else {
        beg = rp[row];
        end = rp[row + 1];
    }

    // x-term: issued early, overlaps the gather chain.
    float xtx, xty;
    if (X_BF) {
        unsigned u = ((const unsigned*)xsrc)[(size_t)row * 64 + lane];
        xtx = ALPHA * bf2f(u & 0xffffu);
        xty = ALPHA * bf2f(u >> 16);
    } else {
        float2 xv = ((const float2*)xsrc)[(size_t)row * 64 + lane];
        xtx = ALPHA * xv.x;
        xty = ALPHA * xv.y;
    }

    const float2*   sf = (const float2*)src;
    const unsigned* sb = (const unsigned*)src;

    float ax0 = 0, ay0 = 0, ax1 = 0, ay1 = 0, ax2 = 0, ay2 = 0, ax3 = 0, ay3 = 0;

    auto gather = [&](int col) -> float2 {
        if (SRC_BF) {
            unsigned u = sb[(size_t)col * 64 + lane];
            float2 v;
            v.x = bf2f(u & 0xffffu);
            v.y = bf2f(u >> 16);
            return v;
        } else {
            return sf[(size_t)col * 64 + lane];
        }
    };

    int j = beg;
    // unroll x8: 8 outstanding 256B gathers per wave (csr loads go scalar,
    // VGPR=20 at R5 confirmed 8 gathers in flight).
    for (; j + 7 < end; j += 8) {
        int2 cw0 = csr[j],     cw1 = csr[j + 1], cw2 = csr[j + 2], cw3 = csr[j + 3];
        int2 cw4 = csr[j + 4], cw5 = csr[j + 5], cw6 = csr[j + 6], cw7 = csr[j + 7];
        float2 v0 = gather(cw0.x);
        float2 v1 = gather(cw1.x);
        float2 v2 = gather(cw2.x);
        float2 v3 = gather(cw3.x);
        float2 v4 = gather(cw4.x);
        float2 v5 = gather(cw5.x);
        float2 v6 = gather(cw6.x);
        float2 v7 = gather(cw7.x);
        float w0 = __int_as_float(cw0.y), w1 = __int_as_float(cw1.y);
        float w2 = __int_as_float(cw2.y), w3 = __int_as_float(cw3.y);
        float w4 = __int_as_float(cw4.y), w5 = __int_as_float(cw5.y);
        float w6 = __int_as_float(cw6.y), w7 = __int_as_float(cw7.y);
        ax0 += w0 * v0.x; ay0 += w0 * v0.y;
        ax1 += w1 * v1.x; ay1 += w1 * v1.y;
        ax2 += w2 * v2.x; ay2 += w2 * v2.y;
        ax3 += w3 * v3.x; ay3 += w3 * v3.y;
        ax0 += w4 * v4.x; ay0 += w4 * v4.y;
        ax1 += w5 * v5.x; ay1 += w5 * v5.y;
        ax2 += w6 * v6.x; ay2 += w6 * v6.y;
        ax3 += w7 * v7.x; ay3 += w7 * v7.y;
    }
    for (; j + 3 < end; j += 4) {
        int2 cw0 = csr[j], cw1 = csr[j + 1], cw2 = csr[j + 2], cw3 = csr[j + 3];
        float2 v0 = gather(cw0.x);
        float2 v1 = gather(cw1.x);
        float2 v2 = gather(cw2.x);
        float2 v3 = gather(cw3.x);
        float w0 = __int_as_float(cw0.y), w1 = __int_as_float(cw1.y);
        float w2 = __int_as_float(cw2.y), w3 = __int_as_float(cw3.y);
        ax0 += w0 * v0.x; ay0 += w0 * v0.y;
        ax1 += w1 * v1.x; ay1 += w1 * v1.y;
        ax2 += w2 * v2.x; ay2 += w2 * v2.y;
        ax3 += w3 * v3.x; ay3 += w3 * v3.y;
    }
    for (; j < end; ++j) {
        int2 cw = csr[j];
        float2 v = gather(cw.x);
        float wv = __int_as_float(cw.y);
        ax0 += wv * v.x; ay0 += wv * v.y;
    }

    float ox = xtx + (ax0 + ax1) + (ax2 + ax3);
    float oy = xty + (ay0 + ay1) + (ay2 + ay3);

    if (DST_BF) {
        ((unsigned*)dst)[(size_t)row * 64 + lane] = f2bf(ox) | (f2bf(oy) << 16);
    } else {
        float2 o; o.x = ox; o.y = oy;
        ((float2*)dst)[(size_t)row * 64 + lane] = o;
    }
}

// ---------- fallback (R0 atomic path) if ws too small ----------

__global__ __launch_bounds__(256) void init_step(const float4* __restrict__ x,
                                                 float4* __restrict__ dst, int n4) {
    int i = blockIdx.x * 256 + threadIdx.x;
    if (i < n4) {
        float4 v = x[i];
        dst[i] = make_float4(ALPHA * v.x, ALPHA * v.y, ALPHA * v.z, ALPHA * v.w);
    }
}

__global__ __launch_bounds__(256) void edge_scatter(const int* __restrict__ rows,
                                                    const int* __restrict__ cols,
                                                    const float* __restrict__ w,
                                                    const float* __restrict__ h,
                                                    float* __restrict__ dst) {
    unsigned t = blockIdx.x * 256u + threadIdx.x;
    unsigned e = t >> 5;
    unsigned l = t & 31u;
    if (e >= N_EDGES) return;
    int r = rows[e];
    int c = cols[e];
    float we = (1.0f - ALPHA) * w[e];
    const float4* hc = (const float4*)(h + (size_t)c * D_FEAT);
    float4 v = hc[l];
    float* dr = dst + (size_t)r * D_FEAT + (size_t)l * 4;
    unsafeAtomicAdd(dr + 0, we * v.x);
    unsafeAtomicAdd(dr + 1, we * v.y);
    unsafeAtomicAdd(dr + 2, we * v.z);
    unsafeAtomicAdd(dr + 3, we * v.w);
}

extern "C" void kernel_launch(void* const* d_in, const int* in_sizes, int n_in,
                              void* d_out, int out_size, void* d_ws, size_t ws_size,
                              hipStream_t stream) {
    const float* x  = (const float*)d_in[0];
    const int*   ei = (const int*)d_in[1];  // [2, E] flat: rows then cols
    const float* ev = (const float*)d_in[2];
    const int* rows = ei;
    const int* cols = ei + N_EDGES;
    float* out = (float*)d_out;

    auto align16 = [](size_t o) { return (o + 15) & ~(size_t)15; };

    // --- padded layout (tier 1): ha, hb, cnt, csrp(64 slots/row), xb ---
    size_t p_off = 0;
    size_t p_ha   = p_off; p_off = align16(p_off + (size_t)N_NODES * D_FEAT * 2);
    size_t p_hb   = p_off; p_off = align16(p_off + (size_t)N_NODES * D_FEAT * 2);
    size_t p_cnt  = p_off; p_off = align16(p_off + (size_t)N_NODES * 4);
    size_t p_csr  = p_off; p_off = align16(p_off + (size_t)N_NODES * MAXDEG * 8);
    size_t p_xb   = p_off; p_off = align16(p_off + (size_t)N_NODES * D_FEAT * 2);
    size_t need_pad = p_off;  // ~128.6 MB

    // --- compact layout (tiers 2/3): ha, hb, rowptr, cursor, partial, csr, [xb] ---
    size_t c_off = 0;
    size_t c_ha      = c_off; c_off = align16(c_off + (size_t)N_NODES * D_FEAT * 2);
    size_t c_hb      = c_off; c_off = align16(c_off + (size_t)N_NODES * D_FEAT * 2);
    size_t c_rowptr  = c_off; c_off = align16(c_off + (size_t)(N_NODES + 1) * 4);
    size_t c_cursor  = c_off; c_off = align16(c_off + (size_t)N_NODES * 4);
    size_t c_partial = c_off; c_off = align16(c_off + (size_t)SCAN_NBLK * 4);
    size_t c_csr     = c_off; c_off = align16(c_off + (size_t)N_EDGES * 8);
    size_t need_base = c_off;  // ~64.8 MB
    size_t c_xb      = c_off; c_off = align16(c_off + (size_t)N_NODES * D_FEAT * 2);
    size_t need_xb   = c_off;  // ~90.4 MB

    const int row_blocks = (N_NODES * 64 + 255) / 256;  // 25000 (1 wave/row)
    const float2* x2 = (const float2*)x;

    if (ws_size >= need_pad) {
        // ---- tier 1: padded CSR, col-sorted rows, no hist/scan ----
        char* ws = (char*)d_ws;
        void*     h_a  = (void*)(ws + p_ha);
        void*     h_b  = (void*)(ws + p_hb);
        int*      cnt  = (int*)(ws + p_cnt);
        int2*     csrp = (int2*)(ws + p_csr);
        unsigned* xb   = (unsigned*)(ws + p_xb);

        hipMemsetAsync(cnt, 0, (size_t)N_NODES * 4, stream);
        const int edge_blocks_1t = (N_EDGES + 255) / 256;  // 6250
        scatter_padded<<<edge_blocks_1t, 256, 0, stream>>>(rows, cols, ev, cnt, csrp);
        sort_rows<<<row_blocks, 256, 0, stream>>>(cnt, csrp);

        const int nxb = N_NODES * D_FEAT / 2;
        x_to_bf16<<<(nxb + 255) / 256, 256, 0, stream>>>(x2, xb, nxb);

        row_spmm_t<true, true, true, true><<<row_blocks, 256, 0, stream>>>(
            cnt, csrp, (const void*)xb, (const void*)xb, h_a);
        for (int k = 1; k <= 8; ++k) {
            const void* src = (k & 1) ? h_a : h_b;
            void* dst = (k & 1) ? h_b : h_a;
            row_spmm_t<true, true, true, true><<<row_blocks, 256, 0, stream>>>(
                cnt, csrp, (const void*)xb, src, dst);
        }
        row_spmm_t<true, false, false, true><<<row_blocks, 256, 0, stream>>>(
            cnt, csrp, (const void*)x2, (const void*)h_a, (void*)out);
    } else if (ws_size >= need_base) {
        // ---- tiers 2/3: compact CSR (R5 path) ----
        char* ws = (char*)d_ws;
        void*  h_a     = (void*)(ws + c_ha);
        void*  h_b     = (void*)(ws + c_hb);
        int*   row_ptr = (int*)(ws + c_rowptr);
        int*   cursor  = (int*)(ws + c_cursor);
        int*   partial = (int*)(ws + c_partial);
        int2*  csr     = (int2*)(ws + c_csr);
        unsigned* xb   = (unsigned*)(ws + c_xb);
        const bool has_xb = (ws_size >= need_xb);
        const int edge_blocks_1t = (N_EDGES + 255) / 256;  // 6250

        hipMemsetAsync(cursor, 0, (size_t)N_NODES * 4, stream);
        hist_kernel<<<edge_blocks_1t, 256, 0, stream>>>(rows, cursor);
        scan_partial<<<SCAN_NBLK, 256, 0, stream>>>(cursor, partial);
        scan_top<<<1, 256, 0, stream>>>(partial);
        scan_final<<<SCAN_NBLK, 256, 0, stream>>>(cursor, partial, row_ptr);
        scatter_kernel<<<edge_blocks_1t, 256, 0, stream>>>(rows, cols, ev, cursor, csr);

        if (has_xb) {
            const int nxb = N_NODES * D_FEAT / 2;
            x_to_bf16<<<(nxb + 255) / 256, 256, 0, stream>>>(x2, xb, nxb);
            row_spmm_t<true, true, true, false><<<row_blocks, 256, 0, stream>>>(
                row_ptr, csr, (const void*)xb, (const void*)xb, h_a);
            for (int k = 1; k <= 8; ++k) {
                const void* src = (k & 1) ? h_a : h_b;
                void* dst = (k & 1) ? h_b : h_a;
                row_spmm_t<true, true, true, false><<<row_blocks, 256, 0, stream>>>(
                    row_ptr, csr, (const void*)xb, src, dst);
            }
            row_spmm_t<true, false, false, false><<<row_blocks, 256, 0, stream>>>(
                row_ptr, csr, (const void*)x2, (const void*)h_a, (void*)out);
        } else {
            row_spmm_t<false, true, false, false><<<row_blocks, 256, 0, stream>>>(
                row_ptr, csr, (const void*)x2, (const void*)x, h_a);
            for (int k = 1; k <= 8; ++k) {
                const void* src = (k & 1) ? h_a : h_b;
                void* dst = (k & 1) ? h_b : h_a;
                row_spmm_t<true, true, false, false><<<row_blocks, 256, 0, stream>>>(
                    row_ptr, csr, (const void*)x2, src, dst);
            }
            row_spmm_t<true, false, false, false><<<row_blocks, 256, 0, stream>>>(
                row_ptr, csr, (const void*)x2, (const void*)h_a, (void*)out);
        }
    } else {
        // Fallback: R0 atomic path (needs only the 51.2 MB ping buffer)
        float* wsf = (float*)d_ws;
        const int n4 = N_NODES * D_FEAT / 4;
        const int init_blocks = (n4 + 255) / 256;
        const int edge_blocks = (N_EDGES * 32 + 255) / 256;
        for (int k = 0; k < K_STEPS; ++k) {
            const float* src = (k == 0) ? x : ((k & 1) ? wsf : out);
            float* dst = (k & 1) ? out : wsf;
            init_step<<<init_blocks, 256, 0, stream>>>((const float4*)x, (float4*)dst, n4);
            edge_scatter<<<edge_blocks, 256, 0, stream>>>(rows, cols, ev, src, dst);
        }
    }
}

// Round 5
// 864.566 us; speedup vs baseline: 1.0522x; 1.0522x over previous
//
#include <hip/hip_runtime.h>

// APPNP propagation: h <- (1-alpha) * A @ h + alpha * x, K=10 steps.
// R3: CSR gather, bf16 h buffers (1066.6). R4: nt loads REGRESSED (1270.9).
// R5: unroll x8 + bf16 xb -> 967.6. R6: padded CSR (no hist/scan) -> 885.7.
// R7: per-row col sort -> FAILED (909.7): block generations restart the col
//     sweep, so no temporal alignment; sort_rows cost ~40us for 0 spmm gain.
// R8: (a) remove sort_rows; (b) unroll gathers x16 (16 outstanding 256B
//     gathers/wave). spmm model: 425 MB/step L2-miss traffic at 5.9 TB/s
//     effective = 0.35 lines/cyc/CU, ~2.6x below L2-hit ceiling and below
//     L3 fabric peak -> request/latency-bound; double per-wave MLP.

#define N_NODES 100000
#define N_EDGES 1600000
#define D_FEAT  128
#define ALPHA   0.1f
#define K_STEPS 10
#define MAXDEG  64   // P(Poisson(16) >= 64) ~ 1e-19; guarded anyway

#define SCAN_ELEMS 512
#define SCAN_NBLK  ((N_NODES + SCAN_ELEMS - 1) / SCAN_ELEMS)  // 196

static __device__ __forceinline__ float bf2f(unsigned u16) {
    return __uint_as_float(u16 << 16);
}
static __device__ __forceinline__ unsigned f2bf(float f) {
    unsigned u = __float_as_uint(f);
    return (u + 0x7fffu + ((u >> 16) & 1u)) >> 16;  // round-to-nearest-even
}

// ---------- padded CSR build: one atomic pass, no hist/scan ----------

__global__ __launch_bounds__(256) void scatter_padded(const int* __restrict__ rows,
                                                      const int* __restrict__ cols,
                                                      const float* __restrict__ w,
                                                      int* __restrict__ cnt,
                                                      int2* __restrict__ csrp) {
    int e = blockIdx.x * 256 + threadIdx.x;
    if (e < N_EDGES) {
        int r = rows[e];
        int pos = atomicAdd(&cnt[r], 1);
        if (pos < MAXDEG) {
            int2 cw;
            cw.x = cols[e];
            cw.y = __float_as_int((1.0f - ALPHA) * w[e]);  // fold 0.9 into weight
            csrp[((size_t)r << 6) + pos] = cw;
        }
    }
}

// ---------- compact CSR build (fallback tier, R5 path) ----------

__global__ __launch_bounds__(256) void hist_kernel(const int* __restrict__ rows,
                                                   int* __restrict__ deg) {
    int e = blockIdx.x * 256 + threadIdx.x;
    if (e < N_EDGES) atomicAdd(&deg[rows[e]], 1);
}

__global__ __launch_bounds__(256) void scan_partial(const int* __restrict__ deg,
                                                    int* __restrict__ partial) {
    __shared__ int s[256];
    int b = blockIdx.x, t = threadIdx.x;
    int i0 = b * SCAN_ELEMS + t * 2;
    int v0 = (i0 < N_NODES) ? deg[i0] : 0;
    int v1 = (i0 + 1 < N_NODES) ? deg[i0 + 1] : 0;
    s[t] = v0 + v1;
    __syncthreads();
    for (int off = 128; off > 0; off >>= 1) {
        if (t < off) s[t] += s[t + off];
        __syncthreads();
    }
    if (t == 0) partial[b] = s[0];
}

__global__ __launch_bounds__(256) void scan_top(int* __restrict__ partial) {
    __shared__ int s[256];
    int t = threadIdx.x;
    s[t] = (t < SCAN_NBLK) ? partial[t] : 0;
    __syncthreads();
    for (int off = 1; off < 256; off <<= 1) {
        int v = (t >= off) ? s[t - off] : 0;
        __syncthreads();
        s[t] += v;
        __syncthreads();
    }
    if (t < SCAN_NBLK) partial[t] = (t == 0) ? 0 : s[t - 1];
}

__global__ __launch_bounds__(256) void scan_final(int* __restrict__ deg_cursor,
                                                  const int* __restrict__ partial,
                                                  int* __restrict__ row_ptr) {
    __shared__ int s[256];
    int b = blockIdx.x, t = threadIdx.x;
    int i0 = b * SCAN_ELEMS + t * 2;
    int v0 = (i0 < N_NODES) ? deg_cursor[i0] : 0;
    int v1 = (i0 + 1 < N_NODES) ? deg_cursor[i0 + 1] : 0;
    int pair = v0 + v1;
    s[t] = pair;
    __syncthreads();
    for (int off = 1; off < 256; off <<= 1) {
        int v = (t >= off) ? s[t - off] : 0;
        __syncthreads();
        s[t] += v;
        __syncthreads();
    }
    int ex = partial[b] + s[t] - pair;  // exclusive prefix of element 2t
    if (i0 < N_NODES)     { row_ptr[i0] = ex;          deg_cursor[i0] = ex; }
    if (i0 + 1 < N_NODES) { row_ptr[i0 + 1] = ex + v0; deg_cursor[i0 + 1] = ex + v0; }
    if (b == 0 && t == 0) row_ptr[N_NODES] = N_EDGES;
}

__global__ __launch_bounds__(256) void scatter_kernel(const int* __restrict__ rows,
                                                      const int* __restrict__ cols,
                                                      const float* __restrict__ w,
                                                      int* __restrict__ cursor,
                                                      int2* __restrict__ csr) {
    int e = blockIdx.x * 256 + threadIdx.x;
    if (e < N_EDGES) {
        int pos = atomicAdd(&cursor[rows[e]], 1);
        int2 cw;
        cw.x = cols[e];
        cw.y = __float_as_int((1.0f - ALPHA) * w[e]);  // fold 0.9 into the weight
        csr[pos] = cw;
    }
}

// x fp32 -> packed 2xbf16 per u32 (row-major, 64 u32 per row)
__global__ __launch_bounds__(256) void x_to_bf16(const float2* __restrict__ x2,
                                                 unsigned* __restrict__ xb, int n) {
    int i = blockIdx.x * 256 + threadIdx.x;
    if (i < n) {
        float2 v = x2[i];
        xb[i] = f2bf(v.x) | (f2bf(v.y) << 16);
    }
}

// ---------- propagation step: one wave per row ----------
// SRC_BF/DST_BF: gather src / dst format. X_BF: alpha*x term source format.
// PAD: padded CSR (rp = cnt[], edges at row*64) vs compact (rp = row_ptr[]).

template <bool SRC_BF, bool DST_BF, bool X_BF, bool PAD>
__global__ __launch_bounds__(256) void row_spmm_t(const int* __restrict__ rp,
                                                  const int2* __restrict__ csr,
                                                  const void* __restrict__ xsrc,
                                                  const void* __restrict__ src,
                                                  void* __restrict__ dst) {
    int row = (blockIdx.x * 256 + threadIdx.x) >> 6;
    int lane = threadIdx.x & 63;
    if (row >= N_NODES) return;
    int beg, end;
    if (PAD) {
        int cn = rp[row];
        cn = (cn < MAXDEG) ? cn : MAXDEG;
        beg = row << 6;
        end = beg + cn;
    } else {
        beg = rp[row];
        end = rp[row + 1];
    }

    // x-term: issued early, overlaps the gather chain.
    float xtx, xty;
    if (X_BF) {
        unsigned u = ((const unsigned*)xsrc)[(size_t)row * 64 + lane];
        xtx = ALPHA * bf2f(u & 0xffffu);
        xty = ALPHA * bf2f(u >> 16);
    } else {
        float2 xv = ((const float2*)xsrc)[(size_t)row * 64 + lane];
        xtx = ALPHA * xv.x;
        xty = ALPHA * xv.y;
    }

    const float2*   sf = (const float2*)src;
    const unsigned* sb = (const unsigned*)src;

    float ax[4] = {0.f, 0.f, 0.f, 0.f};
    float ay[4] = {0.f, 0.f, 0.f, 0.f};

    auto gather = [&](int col) -> float2 {
        if (SRC_BF) {
            unsigned u = sb[(size_t)col * 64 + lane];
            float2 v;
            v.x = bf2f(u & 0xffffu);
            v.y = bf2f(u >> 16);
            return v;
        } else {
            return sf[(size_t)col * 64 + lane];
        }
    };

    int j = beg;
    // unroll x16: 16 outstanding 256B gathers per wave (latency-bound gather
    // path; VGPR stays <=64 so full 8 waves/SIMD occupancy). All array
    // indices are compile-time after full unroll (no scratch).
    while (j + 16 <= end) {
        int2 cw[16];
        #pragma unroll
        for (int u = 0; u < 16; ++u) cw[u] = csr[j + u];
        float2 v[16];
        #pragma unroll
        for (int u = 0; u < 16; ++u) v[u] = gather(cw[u].x);
        #pragma unroll
        for (int u = 0; u < 16; ++u) {
            float wv = __int_as_float(cw[u].y);
            ax[u & 3] += wv * v[u].x;
            ay[u & 3] += wv * v[u].y;
        }
        j += 16;
    }
    while (j + 8 <= end) {
        int2 cw[8];
        #pragma unroll
        for (int u = 0; u < 8; ++u) cw[u] = csr[j + u];
        float2 v[8];
        #pragma unroll
        for (int u = 0; u < 8; ++u) v[u] = gather(cw[u].x);
        #pragma unroll
        for (int u = 0; u < 8; ++u) {
            float wv = __int_as_float(cw[u].y);
            ax[u & 3] += wv * v[u].x;
            ay[u & 3] += wv * v[u].y;
        }
        j += 8;
    }
    while (j + 4 <= end) {
        int2 cw[4];
        #pragma unroll
        for (int u = 0; u < 4; ++u) cw[u] = csr[j + u];
        float2 v[4];
        #pragma unroll
        for (int u = 0; u < 4; ++u) v[u] = gather(cw[u].x);
        #pragma unroll
        for (int u = 0; u < 4; ++u) {
            float wv = __int_as_float(cw[u].y);
            ax[u] += wv * v[u].x;
            ay[u] += wv * v[u].y;
        }
        j += 4;
    }
    for (; j < end; ++j) {
        int2 cw = csr[j];
        float2 v = gather(cw.x);
        float wv = __int_as_float(cw.y);
        ax[0] += wv * v.x;
        ay[0] += wv * v.y;
    }

    float ox = xtx + (ax[0] + ax[1]) + (ax[2] + ax[3]);
    float oy = xty + (ay[0] + ay[1]) + (ay[2] + ay[3]);

    if (DST_BF) {
        ((unsigned*)dst)[(size_t)row * 64 + lane] = f2bf(ox) | (f2bf(oy) << 16);
    } else {
        float2 o; o.x = ox; o.y = oy;
        ((float2*)dst)[(size_t)row * 64 + lane] = o;
    }
}

// ---------- fallback (R0 atomic path) if ws too small ----------

__global__ __launch_bounds__(256) void init_step(const float4* __restrict__ x,
                                                 float4* __restrict__ dst, int n4) {
    int i = blockIdx.x * 256 + threadIdx.x;
    if (i < n4) {
        float4 v = x[i];
        dst[i] = make_float4(ALPHA * v.x, ALPHA * v.y, ALPHA * v.z, ALPHA * v.w);
    }
}

__global__ __launch_bounds__(256) void edge_scatter(const int* __restrict__ rows,
                                                    const int* __restrict__ cols,
                                                    const float* __restrict__ w,
                                                    const float* __restrict__ h,
                                                    float* __restrict__ dst) {
    unsigned t = blockIdx.x * 256u + threadIdx.x;
    unsigned e = t >> 5;
    unsigned l = t & 31u;
    if (e >= N_EDGES) return;
    int r = rows[e];
    int c = cols[e];
    float we = (1.0f - ALPHA) * w[e];
    const float4* hc = (const float4*)(h + (size_t)c * D_FEAT);
    float4 v = hc[l];
    float* dr = dst + (size_t)r * D_FEAT + (size_t)l * 4;
    unsafeAtomicAdd(dr + 0, we * v.x);
    unsafeAtomicAdd(dr + 1, we * v.y);
    unsafeAtomicAdd(dr + 2, we * v.z);
    unsafeAtomicAdd(dr + 3, we * v.w);
}

extern "C" void kernel_launch(void* const* d_in, const int* in_sizes, int n_in,
                              void* d_out, int out_size, void* d_ws, size_t ws_size,
                              hipStream_t stream) {
    const float* x  = (const float*)d_in[0];
    const int*   ei = (const int*)d_in[1];  // [2, E] flat: rows then cols
    const float* ev = (const float*)d_in[2];
    const int* rows = ei;
    const int* cols = ei + N_EDGES;
    float* out = (float*)d_out;

    auto align16 = [](size_t o) { return (o + 15) & ~(size_t)15; };

    // --- padded layout (tier 1): ha, hb, cnt, csrp(64 slots/row), xb ---
    size_t p_off = 0;
    size_t p_ha   = p_off; p_off = align16(p_off + (size_t)N_NODES * D_FEAT * 2);
    size_t p_hb   = p_off; p_off = align16(p_off + (size_t)N_NODES * D_FEAT * 2);
    size_t p_cnt  = p_off; p_off = align16(p_off + (size_t)N_NODES * 4);
    size_t p_csr  = p_off; p_off = align16(p_off + (size_t)N_NODES * MAXDEG * 8);
    size_t p_xb   = p_off; p_off = align16(p_off + (size_t)N_NODES * D_FEAT * 2);
    size_t need_pad = p_off;  // ~128.6 MB

    // --- compact layout (tiers 2/3): ha, hb, rowptr, cursor, partial, csr, [xb] ---
    size_t c_off = 0;
    size_t c_ha      = c_off; c_off = align16(c_off + (size_t)N_NODES * D_FEAT * 2);
    size_t c_hb      = c_off; c_off = align16(c_off + (size_t)N_NODES * D_FEAT * 2);
    size_t c_rowptr  = c_off; c_off = align16(c_off + (size_t)(N_NODES + 1) * 4);
    size_t c_cursor  = c_off; c_off = align16(c_off + (size_t)N_NODES * 4);
    size_t c_partial = c_off; c_off = align16(c_off + (size_t)SCAN_NBLK * 4);
    size_t c_csr     = c_off; c_off = align16(c_off + (size_t)N_EDGES * 8);
    size_t need_base = c_off;  // ~64.8 MB
    size_t c_xb      = c_off; c_off = align16(c_off + (size_t)N_NODES * D_FEAT * 2);
    size_t need_xb   = c_off;  // ~90.4 MB

    const int row_blocks = (N_NODES * 64 + 255) / 256;  // 25000 (1 wave/row)
    const float2* x2 = (const float2*)x;

    if (ws_size >= need_pad) {
        // ---- tier 1: padded CSR, no hist/scan ----
        char* ws = (char*)d_ws;
        void*     h_a  = (void*)(ws + p_ha);
        void*     h_b  = (void*)(ws + p_hb);
        int*      cnt  = (int*)(ws + p_cnt);
        int2*     csrp = (int2*)(ws + p_csr);
        unsigned* xb   = (unsigned*)(ws + p_xb);

        hipMemsetAsync(cnt, 0, (size_t)N_NODES * 4, stream);
        const int edge_blocks_1t = (N_EDGES + 255) / 256;  // 6250
        scatter_padded<<<edge_blocks_1t, 256, 0, stream>>>(rows, cols, ev, cnt, csrp);

        const int nxb = N_NODES * D_FEAT / 2;
        x_to_bf16<<<(nxb + 255) / 256, 256, 0, stream>>>(x2, xb, nxb);

        row_spmm_t<true, true, true, true><<<row_blocks, 256, 0, stream>>>(
            cnt, csrp, (const void*)xb, (const void*)xb, h_a);
        for (int k = 1; k <= 8; ++k) {
            const void* src = (k & 1) ? h_a : h_b;
            void* dst = (k & 1) ? h_b : h_a;
            row_spmm_t<true, true, true, true><<<row_blocks, 256, 0, stream>>>(
                cnt, csrp, (const void*)xb, src, dst);
        }
        row_spmm_t<true, false, false, true><<<row_blocks, 256, 0, stream>>>(
            cnt, csrp, (const void*)x2, (const void*)h_a, (void*)out);
    } else if (ws_size >= need_base) {
        // ---- tiers 2/3: compact CSR (R5 path) ----
        char* ws = (char*)d_ws;
        void*  h_a     = (void*)(ws + c_ha);
        void*  h_b     = (void*)(ws + c_hb);
        int*   row_ptr = (int*)(ws + c_rowptr);
        int*   cursor  = (int*)(ws + c_cursor);
        int*   partial = (int*)(ws + c_partial);
        int2*  csr     = (int2*)(ws + c_csr);
        unsigned* xb   = (unsigned*)(ws + c_xb);
        const bool has_xb = (ws_size >= need_xb);
        const int edge_blocks_1t = (N_EDGES + 255) / 256;  // 6250

        hipMemsetAsync(cursor, 0, (size_t)N_NODES * 4, stream);
        hist_kernel<<<edge_blocks_1t, 256, 0, stream>>>(rows, cursor);
        scan_partial<<<SCAN_NBLK, 256, 0, stream>>>(cursor, partial);
        scan_top<<<1, 256, 0, stream>>>(partial);
        scan_final<<<SCAN_NBLK, 256, 0, stream>>>(cursor, partial, row_ptr);
        scatter_kernel<<<edge_blocks_1t, 256, 0, stream>>>(rows, cols, ev, cursor, csr);

        if (has_xb) {
            const int nxb = N_NODES * D_FEAT / 2;
            x_to_bf16<<<(nxb + 255) / 256, 256, 0, stream>>>(x2, xb, nxb);
            row_spmm_t<true, true, true, false><<<row_blocks, 256, 0, stream>>>(
                row_ptr, csr, (const void*)xb, (const void*)xb, h_a);
            for (int k = 1; k <= 8; ++k) {
                const void* src = (k & 1) ? h_a : h_b;
                void* dst = (k & 1) ? h_b : h_a;
                row_spmm_t<true, true, true, false><<<row_blocks, 256, 0, stream>>>(
                    row_ptr, csr, (const void*)xb, src, dst);
            }
            row_spmm_t<true, false, false, false><<<row_blocks, 256, 0, stream>>>(
                row_ptr, csr, (const void*)x2, (const void*)h_a, (void*)out);
        } else {
            row_spmm_t<false, true, false, false><<<row_blocks, 256, 0, stream>>>(
                row_ptr, csr, (const void*)x2, (const void*)x, h_a);
            for (int k = 1; k <= 8; ++k) {
                const void* src = (k & 1) ? h_a : h_b;
                void* dst = (k & 1) ? h_b : h_a;
                row_spmm_t<true, true, false, false><<<row_blocks, 256, 0, stream>>>(
                    row_ptr, csr, (const void*)x2, src, dst);
            }
            row_spmm_t<true, false, false, false><<<row_blocks, 256, 0, stream>>>(
                row_ptr, csr, (const void*)x2, (const void*)h_a, (void*)out);
        }
    } else {
        // Fallback: R0 atomic path (needs only the 51.2 MB ping buffer)
        float* wsf = (float*)d_ws;
        const int n4 = N_NODES * D_FEAT / 4;
        const int init_blocks = (n4 + 255) / 256;
        const int edge_blocks = (N_EDGES * 32 + 255) / 256;
        for (int k = 0; k < K_STEPS; ++k) {
            const float* src = (k == 0) ? x : ((k & 1) ? wsf : out);
            float* dst = (k & 1) ? out : wsf;
            init_step<<<init_blocks, 256, 0, stream>>>((const float4*)x, (float4*)dst, n4);
            edge_scatter<<<edge_blocks, 256, 0, stream>>>(rows, cols, ev, src, dst);
        }
    }
}